// Round 1
// baseline (12907.826 us; speedup 1.0000x reference)
//
#include <hip/hip_runtime.h>

typedef _Float16 half_t;
typedef _Float16 f16x2 __attribute__((ext_vector_type(2)));
typedef _Float16 f16x8 __attribute__((ext_vector_type(8)));
typedef float f32x4 __attribute__((ext_vector_type(4)));

#define B_SZ 64
#define T_SZ 2048
#define F_SZ 256
#define H_SZ 512
#define O_SZ 128

#if defined(__has_builtin)
#if __has_builtin(__builtin_amdgcn_fdot2)
#define HAS_FDOT2 1
#endif
#endif
#ifndef HAS_FDOT2
#define HAS_FDOT2 0
#endif

// ---------------- prep kernels ----------------

__global__ void cvt_f32_f16(const float* __restrict__ src, half_t* __restrict__ dst, int n) {
    int i = blockIdx.x * 256 + threadIdx.x;
    if (i < n) dst[i] = (half_t)src[i];
}

// Pack W_hh [512,512] f32 (row-major [j][k]) into fp16 pair layout:
// half2 index ((s*64 + k2)*128 + c)*4 + r  holds { W[j][k], W[j][k+1] }
// with j = c + 128*r, k = 128*s + 2*k2.
// Thread (c, s=tid>>7) in the rec kernel then loads one uint4 (r=0..3) per k-pair,
// fully coalesced (lanes = consecutive c).
__global__ void pack_whh(const float* __restrict__ W, half_t* __restrict__ Wp) {
    int i = blockIdx.x * 256 + threadIdx.x;   // i in [0, 131072) half2 units
    int r  = i & 3;
    int c  = (i >> 2) & 127;
    int k2 = (i >> 9) & 63;
    int s  = i >> 15;
    int j = c + 128 * r;
    int k = 128 * s + 2 * k2;
    Wp[2 * i]     = (half_t)W[j * H_SZ + k];
    Wp[2 * i + 1] = (half_t)W[j * H_SZ + k + 1];
}

// ---------------- input-projection GEMM (MFMA f16) ----------------
// C[m][n] = sum_k A[m][k] * Bw[n][k] + bias1[n] + bias2[n], N = 512 fixed.
// Tiles: 64x64 per WG (4 waves, each wave 16 rows x 64 cols via 4 MFMA col-tiles).
// A/B fragments loaded directly from global (B=weights stay L2-resident).
template<bool A_F32, int K>
__global__ __launch_bounds__(256) void gemm_xp(const void* __restrict__ Aptr,
                                               const half_t* __restrict__ Bw,
                                               const float* __restrict__ bias1,
                                               const float* __restrict__ bias2,
                                               half_t* __restrict__ Cout)
{
    const int nt   = blockIdx.x & 7;     // N/64 = 8
    const int mt   = blockIdx.x >> 3;
    const int wave = threadIdx.x >> 6;
    const int lane = threadIdx.x & 63;
    const int mrow = mt * 64 + wave * 16 + (lane & 15);
    const int koff = (lane >> 4) * 8;

    f32x4 acc[4];
#pragma unroll
    for (int i = 0; i < 4; i++) acc[i] = (f32x4){0.f, 0.f, 0.f, 0.f};

#pragma unroll 2
    for (int k0 = 0; k0 < K; k0 += 32) {
        f16x8 a;
        if (A_F32) {
            const float* ap = (const float*)Aptr + (size_t)mrow * K + (k0 + koff);
            float4 v0 = ((const float4*)ap)[0];
            float4 v1 = ((const float4*)ap)[1];
            a[0] = (half_t)v0.x; a[1] = (half_t)v0.y; a[2] = (half_t)v0.z; a[3] = (half_t)v0.w;
            a[4] = (half_t)v1.x; a[5] = (half_t)v1.y; a[6] = (half_t)v1.z; a[7] = (half_t)v1.w;
        } else {
            const half_t* ap = (const half_t*)Aptr + (size_t)mrow * K + (k0 + koff);
            a = *(const f16x8*)ap;
        }
#pragma unroll
        for (int cb = 0; cb < 4; cb++) {
            const int col = nt * 64 + cb * 16 + (lane & 15);
            f16x8 bfrag = *(const f16x8*)(Bw + (size_t)col * K + (k0 + koff));
            acc[cb] = __builtin_amdgcn_mfma_f32_16x16x32_f16(a, bfrag, acc[cb], 0, 0, 0);
        }
    }
    // C/D layout (m89-verified, dtype-independent): col = lane&15, row = (lane>>4)*4 + reg
    const int rbase = mt * 64 + wave * 16 + (lane >> 4) * 4;
#pragma unroll
    for (int cb = 0; cb < 4; cb++) {
        const int col = nt * 64 + cb * 16 + (lane & 15);
        const float bsum = bias1[col] + bias2[col];
#pragma unroll
        for (int r = 0; r < 4; r++) {
            Cout[(size_t)(rbase + r) * H_SZ + col] = (half_t)(acc[cb][r] + bsum);
        }
    }
}

// ---------------- recurrence kernel ----------------
// One WG per batch row. 512 threads: thread (c = tid&127, s = tid>>7) computes
// outputs j in {c, c+128, c+256, c+384} over k-slice [128s, 128s+128), via
// v_dot2_f32_f16 on fp16 pairs (h broadcast from LDS). 4 partials per output
// reduced through LDS, then xp add + tanh + h update. 2 barriers/step.
__global__ __launch_bounds__(512) void rnn_rec(half_t* xpres,          // [B,T,512] xp in, res out (in-place)
                                               const int store_res,
                                               const half_t* __restrict__ Wp,  // packed 512KB
                                               const float* __restrict__ h0,   // [512]
                                               float* hT)                      // [B,512] or nullptr
{
    __shared__ __align__(16) half_t h_sh[H_SZ];
    __shared__ float part[4 * H_SZ];

    const int tid = threadIdx.x;
    const int b   = blockIdx.x;
    const int c   = tid & 127;
    const int s   = tid >> 7;

    h_sh[tid] = (half_t)h0[tid];
    __syncthreads();

    const uint4* __restrict__ Wp4 = (const uint4*)Wp;
    const uint4* hs4 = (const uint4*)h_sh;
    const uint4* wpt = Wp4 + ((size_t)s * 64) * 128 + c;
    const size_t base = (size_t)b * T_SZ * H_SZ;

    for (int t = 0; t < T_SZ; t++) {
        float acc0 = 0.f, acc1 = 0.f, acc2 = 0.f, acc3 = 0.f;
#pragma unroll
        for (int blk = 0; blk < 4; blk++) {
            unsigned int hreg[16];
#pragma unroll
            for (int i = 0; i < 4; i++) {
                uint4 v = hs4[16 * s + blk * 4 + i];   // broadcast read (wave-uniform addr)
                hreg[4 * i + 0] = v.x; hreg[4 * i + 1] = v.y;
                hreg[4 * i + 2] = v.z; hreg[4 * i + 3] = v.w;
            }
#pragma unroll
            for (int l = 0; l < 16; l++) {
                uint4 w = wpt[(blk * 16 + l) * 128];   // 16B/lane, coalesced over c
                f16x2 h2 = __builtin_bit_cast(f16x2, hreg[l]);
#if HAS_FDOT2
                acc0 = __builtin_amdgcn_fdot2(__builtin_bit_cast(f16x2, w.x), h2, acc0, false);
                acc1 = __builtin_amdgcn_fdot2(__builtin_bit_cast(f16x2, w.y), h2, acc1, false);
                acc2 = __builtin_amdgcn_fdot2(__builtin_bit_cast(f16x2, w.z), h2, acc2, false);
                acc3 = __builtin_amdgcn_fdot2(__builtin_bit_cast(f16x2, w.w), h2, acc3, false);
#else
                {
                    f16x2 w0 = __builtin_bit_cast(f16x2, w.x);
                    f16x2 w1 = __builtin_bit_cast(f16x2, w.y);
                    f16x2 w2 = __builtin_bit_cast(f16x2, w.z);
                    f16x2 w3 = __builtin_bit_cast(f16x2, w.w);
                    acc0 += (float)w0[0] * (float)h2[0] + (float)w0[1] * (float)h2[1];
                    acc1 += (float)w1[0] * (float)h2[0] + (float)w1[1] * (float)h2[1];
                    acc2 += (float)w2[0] * (float)h2[0] + (float)w2[1] * (float)h2[1];
                    ac3:
                    acc3 += (float)w3[0] * (float)h2[0] + (float)w3[1] * (float)h2[1];
                }
#endif
            }
        }
        // partials: bank-stride is conflict-free (consecutive c lanes)
        part[s * H_SZ + c]       = acc0;
        part[s * H_SZ + c + 128] = acc1;
        part[s * H_SZ + c + 256] = acc2;
        part[s * H_SZ + c + 384] = acc3;
        __syncthreads();   // partials visible; all h_sh reads of this step done

        const size_t idx = base + (size_t)t * H_SZ + tid;
        float y = (float)xpres[idx]
                + part[tid] + part[H_SZ + tid] + part[2 * H_SZ + tid] + part[3 * H_SZ + tid];
        float hn = tanhf(y);
        if (store_res) xpres[idx] = (half_t)hn;
        if (hT != nullptr && t == T_SZ - 1) hT[(size_t)b * H_SZ + tid] = hn;
        h_sh[tid] = (half_t)hn;
        __syncthreads();   // h_sh update visible for next step
    }
}

// ---------------- head: out[b][o] = dot(hT[b], W_fc[o]) + b_fc[o] ----------------
__global__ __launch_bounds__(128) void head_fc(const float* __restrict__ hT,
                                               const float* __restrict__ Wfc,
                                               const float* __restrict__ bfc,
                                               float* __restrict__ out)
{
    __shared__ float hs[H_SZ];
    const int b = blockIdx.x, o = threadIdx.x;
    for (int i = o; i < H_SZ; i += 128) hs[i] = hT[(size_t)b * H_SZ + i];
    __syncthreads();
    const float4* w4 = (const float4*)(Wfc + (size_t)o * H_SZ);
    const float4* h4 = (const float4*)hs;
    float acc = 0.f;
#pragma unroll 4
    for (int k = 0; k < H_SZ / 4; k++) {
        float4 w = w4[k], h = h4[k];
        acc += w.x * h.x + w.y * h.y + w.z * h.z + w.w * h.w;
    }
    out[(size_t)b * O_SZ + o] = acc + bfc[o];
}

// ---------------- launch ----------------

extern "C" void kernel_launch(void* const* d_in, const int* in_sizes, int n_in,
                              void* d_out, int out_size, void* d_ws, size_t ws_size,
                              hipStream_t stream) {
    const float* x     = (const float*)d_in[0];
    const float* W_ih0 = (const float*)d_in[1];
    const float* W_hh0 = (const float*)d_in[2];
    const float* b_ih0 = (const float*)d_in[3];
    const float* b_hh0 = (const float*)d_in[4];
    const float* h0_0  = (const float*)d_in[5];
    const float* W_ih1 = (const float*)d_in[6];
    const float* W_hh1 = (const float*)d_in[7];
    const float* b_ih1 = (const float*)d_in[8];
    const float* b_hh1 = (const float*)d_in[9];
    const float* h0_1  = (const float*)d_in[10];
    const float* W_fc  = (const float*)d_in[11];
    const float* b_fc  = (const float*)d_in[12];

    char* ws = (char*)d_ws;
    size_t off = 0;
    const size_t bufElems = (size_t)B_SZ * T_SZ * H_SZ;          // 67,108,864
    half_t* bufA  = (half_t*)(ws + off); off += bufElems * 2;    // xp0 -> res (in place)
    half_t* bufB  = (half_t*)(ws + off); off += bufElems * 2;    // xp1
    half_t* Wih0h = (half_t*)(ws + off); off += (size_t)H_SZ * F_SZ * 2;
    half_t* Wih1h = (half_t*)(ws + off); off += (size_t)H_SZ * H_SZ * 2;
    half_t* Wp0   = (half_t*)(ws + off); off += (size_t)H_SZ * H_SZ * 2;
    half_t* Wp1   = (half_t*)(ws + off); off += (size_t)H_SZ * H_SZ * 2;
    float*  hTbuf = (float*)(ws + off);  off += (size_t)B_SZ * H_SZ * 4;

    const int M = B_SZ * T_SZ;   // 131072

    // prep: weight casts / packing
    cvt_f32_f16<<<(H_SZ * F_SZ + 255) / 256, 256, 0, stream>>>(W_ih0, Wih0h, H_SZ * F_SZ);
    cvt_f32_f16<<<(H_SZ * H_SZ + 255) / 256, 256, 0, stream>>>(W_ih1, Wih1h, H_SZ * H_SZ);
    pack_whh<<<(H_SZ * H_SZ / 2) / 256, 256, 0, stream>>>(W_hh0, Wp0);
    pack_whh<<<(H_SZ * H_SZ / 2) / 256, 256, 0, stream>>>(W_hh1, Wp1);

    // xp0 = x @ W_ih0^T + b_ih0 + b_hh0
    gemm_xp<true, F_SZ><<<(M / 64) * 8, 256, 0, stream>>>(x, Wih0h, b_ih0, b_hh0, bufA);
    // layer-0 recurrence (res overwrites xp0 in place)
    rnn_rec<<<B_SZ, 512, 0, stream>>>(bufA, 1, Wp0, h0_0, nullptr);
    // xp1 = res @ W_ih1^T + b_ih1 + b_hh1
    gemm_xp<false, H_SZ><<<(M / 64) * 8, 256, 0, stream>>>(bufA, Wih1h, b_ih1, b_hh1, bufB);
    // layer-1 recurrence, keep only final hidden
    rnn_rec<<<B_SZ, 512, 0, stream>>>(bufB, 0, Wp1, h0_1, hTbuf);
    // head
    head_fc<<<B_SZ, 128, 0, stream>>>(hTbuf, W_fc, b_fc, (float*)d_out);
}